// Round 1
// baseline (711.431 us; speedup 1.0000x reference)
//
#include <hip/hip_runtime.h>
#include <cstdint>
#include <cstddef>

// ---------------------------------------------------------------------------
// SRPLayer: out = Psi_c @ x.T @ x, Psi_c = Psi - rowmean(Psi)
//   x   [D=4096][N=8192] fp32
//   Psi [O=2048][N=8192] fp32
//   out [O=2048][N=8192] fp32
// Strategy: bf16 MFMA for both GEMMs (threshold is 2% of |out|max -> huge
// headroom). Workspace layout (needs 176 MB):
//   xb   [D][N] bf16  @ 0        (64 MB)  - B^T operand of GEMM1
//   xtb  [N][D] bf16  @ 64 MB    (64 MB)  - B^T operand of GEMM2
//   pc   [O][N] bf16  @ 128 MB   (32 MB)  - centered Psi, A of GEMM1
//   tmpb [O][D] bf16  @ 160 MB   (16 MB)  - GEMM1 out, A of GEMM2
// ---------------------------------------------------------------------------

typedef __bf16 bf16x8 __attribute__((ext_vector_type(8)));
typedef float f32x4 __attribute__((ext_vector_type(4)));

__device__ __forceinline__ unsigned short f2bf(float f) {
  // round-to-nearest-even fp32 -> bf16 (inputs finite; no NaN handling)
  unsigned u = __builtin_bit_cast(unsigned, f);
  u += 0x7FFFu + ((u >> 16) & 1u);
  return (unsigned short)(u >> 16);
}

__device__ __forceinline__ void gload_lds16(const void* g, void* l) {
  // async global->LDS, 16B per lane; LDS dest is wave-uniform base + lane*16,
  // our per-lane pointer equals exactly that (linear chunk layout).
  __builtin_amdgcn_global_load_lds(
      (const __attribute__((address_space(1))) unsigned int*)g,
      (__attribute__((address_space(3))) unsigned int*)l, 16, 0, 0);
}

// ---------------- Psi centering: one block per row --------------------------
__global__ void center_psi_kernel(const float* __restrict__ Psi,
                                  unsigned short* __restrict__ pc, int N) {
  int row = blockIdx.x;
  const float4* src = (const float4*)(Psi + (size_t)row * N);
  int n4 = N >> 2;
  float s = 0.f;
  for (int i = threadIdx.x; i < n4; i += blockDim.x) {
    float4 v = src[i];
    s += (v.x + v.y) + (v.z + v.w);
  }
#pragma unroll
  for (int off = 32; off > 0; off >>= 1) s += __shfl_down(s, off);
  __shared__ float red[4];
  if ((threadIdx.x & 63) == 0) red[threadIdx.x >> 6] = s;
  __syncthreads();
  float mean = (red[0] + red[1] + red[2] + red[3]) / (float)N;
  ushort4* dst = (ushort4*)(pc + (size_t)row * N);
  for (int i = threadIdx.x; i < n4; i += blockDim.x) {
    float4 v = src[i];
    ushort4 o;
    o.x = f2bf(v.x - mean);
    o.y = f2bf(v.y - mean);
    o.z = f2bf(v.z - mean);
    o.w = f2bf(v.w - mean);
    dst[i] = o;
  }
}

// ---------------- straight fp32 -> bf16 convert -----------------------------
__global__ void convert_bf16_kernel(const float* __restrict__ in,
                                    unsigned short* __restrict__ out,
                                    long n4) {
  long stride = (long)gridDim.x * blockDim.x;
  for (long i = (long)blockIdx.x * blockDim.x + threadIdx.x; i < n4; i += stride) {
    float4 v = ((const float4*)in)[i];
    ushort4 o;
    o.x = f2bf(v.x);
    o.y = f2bf(v.y);
    o.z = f2bf(v.z);
    o.w = f2bf(v.w);
    ((ushort4*)out)[i] = o;
  }
}

// ---------------- transpose + convert: xt[n][d] = bf16(x[d][n]) -------------
__global__ void transpose_convert_kernel(const float* __restrict__ x,
                                         unsigned short* __restrict__ xt,
                                         int D, int N) {
  __shared__ float tile[32][33];  // +1 pad: conflict-free transpose
  int n0 = blockIdx.x * 32, d0 = blockIdx.y * 32;
  int tx = threadIdx.x, ty = threadIdx.y;  // block (32, 8)
#pragma unroll
  for (int i = 0; i < 4; i++)
    tile[ty + 8 * i][tx] = x[(size_t)(d0 + ty + 8 * i) * N + n0 + tx];
  __syncthreads();
#pragma unroll
  for (int i = 0; i < 4; i++)
    xt[(size_t)(n0 + ty + 8 * i) * D + d0 + tx] = f2bf(tile[tx][ty + 8 * i]);
}

// ---------------- NT GEMM: C[M][Nc] = A[M][K] * B[Nc][K]^T (bf16 in) --------
// m97 structure: 128x128 tile, BK=32, 4 waves (2x2), 4x4 16x16x32 frags/wave,
// single-buffer LDS via global_load_lds width=16, 2 barriers per K-step.
template <typename OutT>
__global__ void gemm_nt_kernel(const unsigned short* __restrict__ A,
                               const unsigned short* __restrict__ B,
                               OutT* __restrict__ C,
                               int M, int Nc, int K) {
  constexpr int BM = 128, BN = 128, BK = 32;
  __shared__ unsigned short As[BM * BK];  // [row][k], 64B rows, linear
  __shared__ unsigned short Bs[BN * BK];

  // XCD-aware bijective swizzle (both grids have nwg % 8 == 0)
  int nwg = gridDim.x * gridDim.y;
  int wgid = blockIdx.y * gridDim.x + blockIdx.x;
  int cpx = nwg >> 3;
  int swz = (wgid & 7) * cpx + (wgid >> 3);
  int bx = swz % gridDim.x, by = swz / gridDim.x;

  int tileM = by * BM, tileN = bx * BN;
  int t = threadIdx.x, lane = t & 63, wave = t >> 6;
  int wm = wave >> 1, wn = wave & 1;  // 2x2 wave grid, 64x64 per wave

  const unsigned short* Abase = A + (size_t)tileM * K;
  const unsigned short* Bbase = B + (size_t)tileN * K;
  // staging chunk for this thread: chunk c covers row c/4, k-quarter c%4 (16B)
  int r0 = t >> 2, kc = t & 3;

  f32x4 acc[4][4] = {};

  for (int k0 = 0; k0 < K; k0 += BK) {
    __syncthreads();  // previous iter's ds_reads done before overwrite
    gload_lds16(Abase + (size_t)r0 * K + k0 + kc * 8, (char*)As + t * 16);
    gload_lds16(Abase + (size_t)(r0 + 64) * K + k0 + kc * 8,
                (char*)As + t * 16 + 4096);
    gload_lds16(Bbase + (size_t)r0 * K + k0 + kc * 8, (char*)Bs + t * 16);
    gload_lds16(Bbase + (size_t)(r0 + 64) * K + k0 + kc * 8,
                (char*)Bs + t * 16 + 4096);
    __syncthreads();  // compiler emits vmcnt(0) drain before barrier

    int kch = (lane >> 4) * 8;  // k-chunk of 8 bf16 for this lane
    int rsel = lane & 15;       // row-in-fragment
    bf16x8 aF[4], bF[4];
#pragma unroll
    for (int s = 0; s < 4; s++) {
      aF[s] = *(const bf16x8*)&As[(wm * 64 + s * 16 + rsel) * BK + kch];
      bF[s] = *(const bf16x8*)&Bs[(wn * 64 + s * 16 + rsel) * BK + kch];
    }
#pragma unroll
    for (int i = 0; i < 4; i++)
#pragma unroll
      for (int j = 0; j < 4; j++)
        acc[i][j] = __builtin_amdgcn_mfma_f32_16x16x32_bf16(aF[i], bF[j],
                                                            acc[i][j], 0, 0, 0);
  }

  // C/D layout (m89/m91 verified): row = (lane>>4)*4 + reg, col = lane&15
  int rbase = tileM + wm * 64 + ((lane >> 4) << 2);
  int cbase = tileN + wn * 64 + (lane & 15);
#pragma unroll
  for (int i = 0; i < 4; i++)
#pragma unroll
    for (int j = 0; j < 4; j++)
#pragma unroll
      for (int r = 0; r < 4; r++) {
        size_t off = (size_t)(rbase + i * 16 + r) * Nc + (cbase + j * 16);
        if constexpr (__is_same(OutT, float))
          C[off] = acc[i][j][r];
        else
          C[off] = f2bf(acc[i][j][r]);
      }
}

// ---------------------------------------------------------------------------
extern "C" void kernel_launch(void* const* d_in, const int* in_sizes, int n_in,
                              void* d_out, int out_size, void* d_ws,
                              size_t ws_size, hipStream_t stream) {
  const int D = 4096, N = 8192, O = 2048;
  const float* x = (const float*)d_in[0];
  const float* Psi = (const float*)d_in[1];
  float* out = (float*)d_out;

  char* ws = (char*)d_ws;
  unsigned short* xb = (unsigned short*)(ws);                         // 64 MB
  unsigned short* xtb = (unsigned short*)(ws + ((size_t)64 << 20));   // 64 MB
  unsigned short* pc = (unsigned short*)(ws + ((size_t)128 << 20));   // 32 MB
  unsigned short* tmpb = (unsigned short*)(ws + ((size_t)160 << 20)); // 16 MB

  center_psi_kernel<<<O, 256, 0, stream>>>(Psi, pc, N);
  convert_bf16_kernel<<<2048, 256, 0, stream>>>(x, xb, (long)D * N / 4);
  transpose_convert_kernel<<<dim3(N / 32, D / 32), dim3(32, 8), 0, stream>>>(
      x, xtb, D, N);
  // GEMM1: tmp[O][D] = pc[O][N] * xb[D][N]^T
  gemm_nt_kernel<unsigned short><<<dim3(D / 128, O / 128), 256, 0, stream>>>(
      pc, xb, tmpb, O, D, N);
  // GEMM2: out[O][N] = tmpb[O][D] * xtb[N][D]^T
  gemm_nt_kernel<float><<<dim3(N / 128, O / 128), 256, 0, stream>>>(
      tmpb, xtb, out, O, N, D);
}

// Round 3
// 523.917 us; speedup vs baseline: 1.3579x; 1.3579x over previous
//
#include <hip/hip_runtime.h>
#include <cstdint>
#include <cstddef>

// ---------------------------------------------------------------------------
// SRPLayer: out = Psi_c @ x.T @ x, Psi_c = Psi - rowmean(Psi)
//   x [4096][8192] f32, Psi [2048][8192] f32, out [2048][8192] f32
// bf16 MFMA GEMMs with the 256-wide 8-phase schedule (T2+T3+T4+T5).
// ws: xb [D][N] bf16 @0 (64MB) | xtb [N][D] bf16 @64MB | pc [O][N] bf16 @128MB
//     | tmpb [O][D] bf16 @160MB
// ---------------------------------------------------------------------------

typedef __bf16 bf16x8 __attribute__((ext_vector_type(8)));
typedef float f32x4 __attribute__((ext_vector_type(4)));

__device__ __forceinline__ unsigned short f2bf(float f) {
  unsigned u = __builtin_bit_cast(unsigned, f);
  u += 0x7FFFu + ((u >> 16) & 1u);
  return (unsigned short)(u >> 16);
}

__device__ __forceinline__ void gload_lds16(const void* g, void* l) {
  // async global->LDS, 16B/lane; LDS dest must be wave-uniform base + lane*16
  __builtin_amdgcn_global_load_lds(
      (const __attribute__((address_space(1))) unsigned int*)g,
      (__attribute__((address_space(3))) unsigned int*)l, 16, 0, 0);
}

__device__ __forceinline__ void barrier_nofence() {
  // raw s_barrier WITHOUT the vmcnt(0) drain __syncthreads would emit;
  // memory clobbers pin loads/stores into their phase.
  asm volatile("" ::: "memory");
  __builtin_amdgcn_s_barrier();
  asm volatile("" ::: "memory");
}
#define WAIT_LGKM0()                                   \
  do {                                                 \
    asm volatile("s_waitcnt lgkmcnt(0)" ::: "memory"); \
    __builtin_amdgcn_sched_barrier(0);                 \
  } while (0)

template <int MH, int NH, int MFR2>
__device__ __forceinline__ void mma_quad(f32x4 (&acc)[2 * MFR2][4],
                                         const bf16x8 (&aF)[MFR2][2],
                                         const bf16x8 (&bF)[2][2]) {
#pragma unroll
  for (int f = 0; f < MFR2; ++f)
#pragma unroll
    for (int g = 0; g < 2; ++g)
#pragma unroll
      for (int kk = 0; kk < 2; ++kk)
        acc[MH * MFR2 + f][NH * 2 + g] = __builtin_amdgcn_mfma_f32_16x16x32_bf16(
            aF[f][kk], bF[g][kk], acc[MH * MFR2 + f][NH * 2 + g], 0, 0, 0);
}

// ---------------- 8-phase NT GEMM: C[M][Nc] = A[M][K] * B[Nc][K]^T ----------
// BN=256, BK=64 fixed. 512 thr = 8 waves (2M x 4N). LDS planes [kk][row][32]
// with chunk swizzle c ^= ((row>>3)&1)<<1 (st_16x32), applied on the
// pre-swizzled global source AND the ds_read address.
template <int BM, typename OutT>
__global__ __launch_bounds__(512, 2) void gemm8p(
    const unsigned short* __restrict__ A, const unsigned short* __restrict__ B,
    OutT* __restrict__ C, int M, int Nc, int K) {
  constexpr int BN = 256, BK = 64;
  constexpr int MFR = BM / 32, MFR2 = MFR / 2;
  constexpr int APLANE = BM * 64;  // bytes per kk-plane
  constexpr int ABUF = 2 * APLANE;
  constexpr int BPLANE = BN * 64, BBUF = 2 * BPLANE;
  __shared__ __align__(1024) char lds[2 * ABUF + 2 * BBUF];
  char* Al = lds;
  char* Bl = lds + 2 * ABUF;

  const int nwg = gridDim.x * gridDim.y;
  const int wgid = blockIdx.y * gridDim.x + blockIdx.x;
  const int swz = (wgid & 7) * (nwg >> 3) + (wgid >> 3);  // nwg % 8 == 0
  const int bx = swz % gridDim.x, by = swz / gridDim.x;
  const int tileM = by * BM, tileN = bx * BN;

  const int t = threadIdx.x, lane = t & 63, wave = t >> 6;
  const int wm = wave >> 2, wn = wave & 3;  // 2M x 4N wave grid
  const int rsel = lane & 15;
  // ds_read chunk byte offset incl. swizzle ((m>>3)&1 == (lane>>3)&1 here)
  const int cs = (((lane >> 4) ^ (((lane >> 3) & 1) << 1)) << 4);

  const unsigned short* Ag = A + (size_t)tileM * K;
  const unsigned short* Bg = B + (size_t)tileN * K;
  // staging source chunk (elements), pre-swizzled: (row>>3)&1 == (t>>5)&1
  const int cgA = (((t & 3) ^ (((t >> 5) & 1) << 1))) * 8;
  const int NT = K / BK;

  auto stageA = [&](int h, int kt) {
    int b2 = kt & 1;
    if constexpr (BM == 256) {
#pragma unroll
      for (int kk = 0; kk < 2; ++kk) {
        int r = h * 128 + (t >> 2);
        gload_lds16(Ag + (size_t)r * K + kt * 64 + kk * 32 + cgA,
                    Al + b2 * ABUF + kk * APLANE + h * 8192 + t * 16);
      }
    } else {  // BM==128: one gload covers both kk planes (per-wave linear)
      int r = h * 64 + ((t >> 2) & 63);
      int kk = t >> 8;
      gload_lds16(Ag + (size_t)r * K + kt * 64 + kk * 32 + cgA,
                  Al + b2 * ABUF + kk * APLANE + h * 4096 + (t & 255) * 16);
    }
  };
  auto stageB = [&](int h, int kt) {
    int b2 = kt & 1;
#pragma unroll
    for (int kk = 0; kk < 2; ++kk) {
      int r = h * 128 + (t >> 2);
      gload_lds16(Bg + (size_t)r * K + kt * 64 + kk * 32 + cgA,
                  Bl + b2 * BBUF + kk * BPLANE + h * 8192 + t * 16);
    }
  };
  auto waitv_steady = [&]() {
    // 3 half-tiles in flight: (kt+2).{A0,B1,A1}
    if constexpr (BM == 256)
      asm volatile("s_waitcnt vmcnt(6)" ::: "memory");
    else
      asm volatile("s_waitcnt vmcnt(4)" ::: "memory");
  };

  f32x4 acc[MFR][4] = {};
  bf16x8 aF[MFR2][2], bF[2][2];

  // prologue: tile0 fully + tile1.{A0,B1,A1}; then tile0 guaranteed landed
  stageA(0, 0); stageB(1, 0); stageA(1, 0); stageB(0, 0);
  stageA(0, 1); stageB(1, 1); stageA(1, 1);
  waitv_steady();
  barrier_nofence();

  for (int kt = 0; kt < NT; ++kt) {
    const char* Ab = Al + (kt & 1) * ABUF;
    const char* Bb = Bl + (kt & 1) * BBUF;
    // -- phase 0: read A(mh0)+B(nh0); stage (kt+1).B0; mma quad (0,0)
#pragma unroll
    for (int f = 0; f < MFR2; ++f)
#pragma unroll
      for (int kk = 0; kk < 2; ++kk)
        aF[f][kk] = *(const bf16x8*)(Ab + kk * APLANE +
                                     ((2 * f + wm) * 16 + rsel) * 64 + cs);
#pragma unroll
    for (int g = 0; g < 2; ++g)
#pragma unroll
      for (int kk = 0; kk < 2; ++kk)
        bF[g][kk] = *(const bf16x8*)(Bb + kk * BPLANE +
                                     ((4 * g + wn) * 16 + rsel) * 64 + cs);
    if (kt + 1 < NT) stageB(0, kt + 1);
    barrier_nofence();
    WAIT_LGKM0();
    __builtin_amdgcn_s_setprio(1);
    mma_quad<0, 0, MFR2>(acc, aF, bF);
    __builtin_amdgcn_s_setprio(0);
    barrier_nofence();
    // -- phase 1: read B(nh1); stage (kt+2).A0; mma quad (0,1)
#pragma unroll
    for (int g = 0; g < 2; ++g)
#pragma unroll
      for (int kk = 0; kk < 2; ++kk)
        bF[g][kk] = *(const bf16x8*)(Bb + kk * BPLANE +
                                     ((4 * (g + 2) + wn) * 16 + rsel) * 64 + cs);
    if (kt + 2 < NT) stageA(0, kt + 2);
    barrier_nofence();
    WAIT_LGKM0();
    __builtin_amdgcn_s_setprio(1);
    mma_quad<0, 1, MFR2>(acc, aF, bF);
    __builtin_amdgcn_s_setprio(0);
    barrier_nofence();
    // -- phase 2: read A(mh1); stage (kt+2).B1; mma quad (1,1)
#pragma unroll
    for (int f = 0; f < MFR2; ++f)
#pragma unroll
      for (int kk = 0; kk < 2; ++kk)
        aF[f][kk] = *(const bf16x8*)(Ab + kk * APLANE +
                                     ((2 * (f + MFR2) + wm) * 16 + rsel) * 64 + cs);
    if (kt + 2 < NT) stageB(1, kt + 2);
    barrier_nofence();
    WAIT_LGKM0();
    __builtin_amdgcn_s_setprio(1);
    mma_quad<1, 1, MFR2>(acc, aF, bF);
    __builtin_amdgcn_s_setprio(0);
    barrier_nofence();
    // -- phase 3: re-read B(nh0); stage (kt+2).A1; mma quad (1,0)
#pragma unroll
    for (int g = 0; g < 2; ++g)
#pragma unroll
      for (int kk = 0; kk < 2; ++kk)
        bF[g][kk] = *(const bf16x8*)(Bb + kk * BPLANE +
                                     ((4 * g + wn) * 16 + rsel) * 64 + cs);
    if (kt + 2 < NT) stageA(1, kt + 2);
    barrier_nofence();
    WAIT_LGKM0();
    __builtin_amdgcn_s_setprio(1);
    mma_quad<1, 0, MFR2>(acc, aF, bF);
    __builtin_amdgcn_s_setprio(0);
    if (kt + 2 < NT)
      waitv_steady();
    else
      asm volatile("s_waitcnt vmcnt(0)" ::: "memory");
    barrier_nofence();
  }

  // epilogue: C/D layout row=(lane>>4)*4+r, col=lane&15 (m89/m91-verified)
#pragma unroll
  for (int f = 0; f < MFR; ++f) {
    int row0 = tileM + (2 * f + wm) * 16 + ((lane >> 4) << 2);
#pragma unroll
    for (int g = 0; g < 4; ++g) {
      int col = tileN + (4 * g + wn) * 16 + rsel;
#pragma unroll
      for (int r = 0; r < 4; ++r) {
        size_t off = (size_t)(row0 + r) * Nc + col;
        if constexpr (__is_same(OutT, float))
          C[off] = acc[f][g][r];
        else
          C[off] = f2bf(acc[f][g][r]);
      }
    }
  }
}

// ---------------- Psi centering: one block per row --------------------------
__global__ void center_psi_kernel(const float* __restrict__ Psi,
                                  unsigned short* __restrict__ pc, int N) {
  int row = blockIdx.x;
  const float4* src = (const float4*)(Psi + (size_t)row * N);
  int n4 = N >> 2;
  float s = 0.f;
  for (int i = threadIdx.x; i < n4; i += blockDim.x) {
    float4 v = src[i];
    s += (v.x + v.y) + (v.z + v.w);
  }
#pragma unroll
  for (int off = 32; off > 0; off >>= 1) s += __shfl_down(s, off);
  __shared__ float red[4];
  if ((threadIdx.x & 63) == 0) red[threadIdx.x >> 6] = s;
  __syncthreads();
  float mean = (red[0] + red[1] + red[2] + red[3]) / (float)N;
  ushort4* dst = (ushort4*)(pc + (size_t)row * N);
  for (int i = threadIdx.x; i < n4; i += blockDim.x) {
    float4 v = src[i];
    ushort4 o;
    o.x = f2bf(v.x - mean);
    o.y = f2bf(v.y - mean);
    o.z = f2bf(v.z - mean);
    o.w = f2bf(v.w - mean);
    dst[i] = o;
  }
}

// ------- fused x -> {xb (bf16), xtb (bf16 transposed)}: reads x once --------
__global__ void ct_kernel(const float* __restrict__ x,
                          unsigned short* __restrict__ xb,
                          unsigned short* __restrict__ xtb, int D, int N) {
  __shared__ float tile[64][65];
  int n0 = blockIdx.x * 64, d0 = blockIdx.y * 64;
  int tx = threadIdx.x, ty = threadIdx.y;  // block (64,4)
#pragma unroll
  for (int i = 0; i < 16; i++) {
    int d = ty + 4 * i;
    float v = x[(size_t)(d0 + d) * N + n0 + tx];
    tile[d][tx] = v;
    xb[(size_t)(d0 + d) * N + n0 + tx] = f2bf(v);
  }
  __syncthreads();
#pragma unroll
  for (int i = 0; i < 16; i++) {
    int nn = ty + 4 * i;
    xtb[(size_t)(n0 + nn) * D + d0 + tx] = f2bf(tile[tx][nn]);
  }
}

// ---------------------------------------------------------------------------
extern "C" void kernel_launch(void* const* d_in, const int* in_sizes, int n_in,
                              void* d_out, int out_size, void* d_ws,
                              size_t ws_size, hipStream_t stream) {
  const int D = 4096, N = 8192, O = 2048;
  const float* x = (const float*)d_in[0];
  const float* Psi = (const float*)d_in[1];
  float* out = (float*)d_out;

  char* ws = (char*)d_ws;
  unsigned short* xb = (unsigned short*)(ws);                          // 64 MB
  unsigned short* xtb = (unsigned short*)(ws + ((size_t)64 << 20));    // 64 MB
  unsigned short* pc = (unsigned short*)(ws + ((size_t)128 << 20));    // 32 MB
  unsigned short* tmpb = (unsigned short*)(ws + ((size_t)160 << 20));  // 16 MB

  center_psi_kernel<<<O, 256, 0, stream>>>(Psi, pc, N);
  ct_kernel<<<dim3(N / 64, D / 64), dim3(64, 4), 0, stream>>>(x, xb, xtb, D, N);
  // GEMM1: tmp[O][D] = pc[O][N] * xb[D][N]^T   (BM=128, grid 16x16=256)
  gemm8p<128, unsigned short><<<dim3(D / 256, O / 128), 512, 0, stream>>>(
      pc, xb, tmpb, O, D, N);
  // GEMM2: out[O][N] = tmpb[O][D] * xtb[N][D]^T (BM=256, grid 32x8=256)
  gemm8p<256, float><<<dim3(N / 256, O / 256), 512, 0, stream>>>(
      tmpb, xtb, out, O, N, D);
}